// Round 4
// baseline (177.729 us; speedup 1.0000x reference)
//
#include <hip/hip_runtime.h>

#define BX 4
#define VX 4
#define NN 1000
#define HEADS_ 4
#define OUTF 32
#define DM 128
#define EE 64000
#define NTOT 4000
#define ETOT 68000
#define CAP 48   // bucket capacity per dst; active degree ~ Poisson(4)+1, P(>47)~0

// ---------------------------------------------------------------------------
// Tiled GEMM: C[M][N] = A[M][K] @ Wt[N][K]^T (+ b1[n] + b2[n])
// 128x64 tile, 256 threads, 8x4 micro-tile, K staged in 64-wide chunks.
// LDS is m-major with k-group XOR swizzle: row r's k-group q lives at
// group q ^ (r & 15). Staging = direct b128 copies (no transpose);
// compute reads are aligned ds_read_b128, 2-addr (A) / 4-addr (B) broadcast,
// conflict-free. 48 KB LDS -> 3 blocks/CU.
// ---------------------------------------------------------------------------
template <int K>
__global__ __launch_bounds__(256) void gemm_kernel(const float* __restrict__ A,
                                                   const float* __restrict__ Wt,
                                                   const float* __restrict__ b1,
                                                   const float* __restrict__ b2,
                                                   float* __restrict__ C,
                                                   int N) {
  __shared__ float As[128 * 64];
  __shared__ float Bs[64 * 64];
  int tid = threadIdx.x;
  int m0 = blockIdx.x * 128, n0 = blockIdx.y * 64;
  int tx = tid & 15, ty = tid >> 4;
  const float4* A4 = (const float4*)A;
  const float4* W4 = (const float4*)Wt;
  float acc[8][4] = {};

  for (int c = 0; c < K / 64; ++c) {
    __syncthreads();  // protect LDS reuse across chunks (no-op cost at c==0)
    {
      int q = tid & 15;   // k-group slot within chunk
      int r0 = tid >> 4;  // 16 rows per pass
#pragma unroll
      for (int p = 0; p < 8; ++p) {  // A: 128 rows
        int r = r0 + p * 16;
        float4 v = A4[(size_t)(m0 + r) * (K / 4) + c * 16 + q];
        *(float4*)&As[r * 64 + ((q ^ (r & 15)) << 2)] = v;
      }
#pragma unroll
      for (int p = 0; p < 4; ++p) {  // B: 64 rows
        int r = r0 + p * 16;
        float4 v = W4[(size_t)(n0 + r) * (K / 4) + c * 16 + q];
        *(float4*)&Bs[r * 64 + ((q ^ (r & 15)) << 2)] = v;
      }
    }
    __syncthreads();
#pragma unroll 4
    for (int q = 0; q < 16; ++q) {
      float4 a[8], b[4];
#pragma unroll
      for (int i = 0; i < 8; ++i) {
        int r = ty * 8 + i;
        a[i] = *(const float4*)&As[r * 64 + ((q ^ (r & 15)) << 2)];
      }
#pragma unroll
      for (int j = 0; j < 4; ++j) {
        int rn = tx * 4 + j;
        b[j] = *(const float4*)&Bs[rn * 64 + ((q ^ (rn & 15)) << 2)];
      }
#pragma unroll
      for (int i = 0; i < 8; ++i)
#pragma unroll
        for (int j = 0; j < 4; ++j)
          acc[i][j] += a[i].x * b[j].x + a[i].y * b[j].y
                     + a[i].z * b[j].z + a[i].w * b[j].w;
    }
  }

  float bd[4] = {0.f, 0.f, 0.f, 0.f};
  int nc = n0 + tx * 4;
  if (b1) { bd[0] = b1[nc]; bd[1] = b1[nc+1]; bd[2] = b1[nc+2]; bd[3] = b1[nc+3]; }
  if (b2) { bd[0] += b2[nc]; bd[1] += b2[nc+1]; bd[2] += b2[nc+2]; bd[3] += b2[nc+3]; }
#pragma unroll
  for (int i = 0; i < 8; ++i) {
    int m = m0 + ty * 8 + i;
    float4 o = make_float4(acc[i][0] + bd[0], acc[i][1] + bd[1],
                           acc[i][2] + bd[2], acc[i][3] + bd[3]);
    *(float4*)&C[(size_t)m * N + nc] = o;
  }
}

// ------------------------------------------------- per-node score halves
// h_flat[j] nonzero only for j<1000 (block b=0,v=0 = hbuf rows 0..999)
__global__ void node_score_kernel(const float* __restrict__ hbuf,
                                  const float* __restrict__ att,
                                  float* __restrict__ ssrc,
                                  float* __restrict__ sdst) {
  int j = blockIdx.x * blockDim.x + threadIdx.x;
  if (j >= NTOT) return;
  if (j < NN) {
#pragma unroll
    for (int h = 0; h < HEADS_; ++h) {
      float a0 = 0.f, a1 = 0.f;
#pragma unroll
      for (int k = 0; k < OUTF; ++k) {
        float g = hbuf[j * DM + h * OUTF + k];
        float lr = g > 0.f ? g : 0.2f * g;
        a0 += att[h * 64 + k] * lr;
        a1 += att[h * 64 + 32 + k] * lr;
      }
      ssrc[j * HEADS_ + h] = a0;
      sdst[j * HEADS_ + h] = a1;
    }
  } else {
#pragma unroll
    for (int h = 0; h < HEADS_; ++h) {
      ssrc[j * HEADS_ + h] = 0.f;
      sdst[j * HEADS_ + h] = 0.f;
    }
  }
}

// ---- per-edge exp(score) + denom atomics + direct bucket adjacency build
// denom covers ALL edges (reference softmax); buckets only active edges
// (src,dst in same graph block). Bucket order is irrelevant to the gather.
__global__ void edge_score_kernel(const int* __restrict__ ei,
                                  const float* __restrict__ ssrc,
                                  const float* __restrict__ sdst,
                                  float* __restrict__ exbuf,
                                  float* __restrict__ denom,
                                  int* __restrict__ cnt,
                                  int2* __restrict__ elist) {
  int e = blockIdx.x * blockDim.x + threadIdx.x;
  if (e >= ETOT) return;
  int s, d;
  if (e < EE) { s = ei[e]; d = ei[EE + e]; }
  else { s = d = e - EE; }  // self loops
#pragma unroll
  for (int h = 0; h < HEADS_; ++h) {
    float sc = ssrc[s * HEADS_ + h] + sdst[d * HEADS_ + h];
    float ex = __expf(sc);  // shift-invariant; scores O(1), no max pass needed
    exbuf[e * HEADS_ + h] = ex;
    atomicAdd(&denom[d * HEADS_ + h], ex);
  }
  if (s / NN == d / NN) {
    int pos = atomicAdd(&cnt[d], 1);
    if (pos < CAP) elist[d * CAP + pos] = make_int2(s, e);
  }
}

// ------------------- gather aggregation: 2 dst/block, float4 per thread
// thread (v, q): out[(b*4+v)*NN+n][4q..4q+3] over bucket edges of dst d
__global__ __launch_bounds__(256) void gather_kernel(const int* __restrict__ cnt,
                                                     const int2* __restrict__ elist,
                                                     const float* __restrict__ exbuf,
                                                     const float* __restrict__ denom,
                                                     const float* __restrict__ hbuf,
                                                     float* __restrict__ out) {
  int li = threadIdx.x >> 7;
  int t = threadIdx.x & 127;
  int d = blockIdx.x * 2 + li;  // global dst node id
  int v = t >> 5, q = t & 31;   // view, float4-col
  int h = q >> 3;
  int b = d / NN, n = d - b * NN;
  float rd = 1.f / (denom[d * HEADS_ + h] + 1e-16f);
  float4 acc = make_float4(0.f, 0.f, 0.f, 0.f);
  int m = cnt[d]; if (m > CAP) m = CAP;
  const int2* el = elist + d * CAP;
  const float* hbase = hbuf + ((size_t)(b * VX + v) * NN) * DM + q * 4;
  for (int i = 0; i < m; ++i) {
    int2 se = el[i];
    float alpha = exbuf[se.y * HEADS_ + h] * rd;
    int sl = se.x - b * NN;
    float4 hv = *(const float4*)(hbase + (size_t)sl * DM);
    acc.x += alpha * hv.x; acc.y += alpha * hv.y;
    acc.z += alpha * hv.z; acc.w += alpha * hv.w;
  }
  *(float4*)&out[((size_t)(b * VX + v) * NN + n) * DM + q * 4] = acc;
}

// ------------------------------------------- attention over V, 2 nodes/block
__global__ __launch_bounds__(256) void attn_kernel(const float* __restrict__ qkv,
                                                   float* __restrict__ ao) {
  int li = threadIdx.x >> 7;
  int t = threadIdx.x & 127;
  int node = blockIdx.x * 2 + li;  // 0..3999
  int b = node / NN, n = node - b * NN;
  __shared__ float qs[2][VX][DM], ks[2][VX][DM], vs[2][VX][DM];
  __shared__ float aw[2][VX][HEADS_][VX];
#pragma unroll
  for (int v = 0; v < VX; ++v) {
    size_t base = (size_t)((b * VX + v) * NN + n) * 384;
    qs[li][v][t] = qkv[base + t];
    ks[li][v][t] = qkv[base + 128 + t];
    vs[li][v][t] = qkv[base + 256 + t];
  }
  __syncthreads();
  if (t < 64) {  // (vq, vk, h) dot products, length 32
    int vq = t >> 4, vk = (t >> 2) & 3, h = t & 3;
    float acc = 0.f;
#pragma unroll
    for (int kd = 0; kd < 32; ++kd)
      acc += qs[li][vq][h * 32 + kd] * ks[li][vk][h * 32 + kd];
    aw[li][vq][h][vk] = acc * 0.17677669529663687f;  // 1/sqrt(32)
  }
  __syncthreads();
  if (t < 16) {  // softmax over vk per (vq, h)
    int vq = t >> 2, h = t & 3;
    float m = aw[li][vq][h][0];
    for (int i = 1; i < 4; ++i) m = fmaxf(m, aw[li][vq][h][i]);
    float e[4], s = 0.f;
    for (int i = 0; i < 4; ++i) { e[i] = __expf(aw[li][vq][h][i] - m); s += e[i]; }
    for (int i = 0; i < 4; ++i) aw[li][vq][h][i] = e[i] / s;
  }
  __syncthreads();
  int h = t >> 5;
#pragma unroll
  for (int vq = 0; vq < VX; ++vq) {
    float acc = 0.f;
#pragma unroll
    for (int vk = 0; vk < VX; ++vk) acc += aw[li][vq][h][vk] * vs[li][vk][t];
    ao[(size_t)((b * VX + vq) * NN + n) * DM + t] = acc;
  }
}

extern "C" void kernel_launch(void* const* d_in, const int* in_sizes, int n_in,
                              void* d_out, int out_size, void* d_ws, size_t ws_size,
                              hipStream_t stream) {
  const float* x    = (const float*)d_in[0];
  const float* W    = (const float*)d_in[1];
  const float* att  = (const float*)d_in[2];
  const float* inw  = (const float*)d_in[3];
  const float* inb  = (const float*)d_in[4];
  const float* outw = (const float*)d_in[5];
  const float* outb = (const float*)d_in[6];
  const float* bias = (const float*)d_in[7];
  const int*   ei   = (const int*)d_in[8];
  float* out = (float*)d_out;

  float* ws = (float*)d_ws;
  // ---- early-phase layout (floats) ----
  float* hbuf  = ws;                      // 2,048,000
  float* ssrc  = hbuf + 2048000;          // 16,000
  float* sdst  = ssrc + 16000;            // 16,000
  float* denom = sdst + 16000;            // 16,000
  int*   cnt   = (int*)(denom + 16000);   // 4,000 (adjacent: one memset)
  float* exbuf = (float*)(cnt + 4000);    // 272,000
  int2*  elist = (int2*)(exbuf + 272000); // 4000*48 int2 = 384,000 ints
  // ---- late-phase layout (aliases early region; gather has completed) ----
  float* ao  = ws;            // aliases hbuf (dead after gather)
  float* qkv = ws + 2048000;  // 6,144,000 (aliases score/adjacency region)
  // peak ws: 8,192,000 floats = 32.8 MB

  hipMemsetAsync(denom, 0, 16000 * sizeof(float) + 4000 * sizeof(int), stream);

  // h = x @ W^T : M=16000, K=64, N=128
  gemm_kernel<64><<<dim3(125, 2), 256, 0, stream>>>(x, W, nullptr, nullptr, hbuf, 128);
  node_score_kernel<<<(NTOT + 255) / 256, 256, 0, stream>>>(hbuf, att, ssrc, sdst);
  edge_score_kernel<<<(ETOT + 255) / 256, 256, 0, stream>>>(ei, ssrc, sdst, exbuf, denom, cnt, elist);
  gather_kernel<<<NTOT / 2, 256, 0, stream>>>(cnt, elist, exbuf, denom, hbuf, out);
  // qkv = hgat @ inw^T + inb : M=16000, K=128, N=384
  gemm_kernel<128><<<dim3(125, 6), 256, 0, stream>>>(out, inw, inb, nullptr, qkv, 384);
  attn_kernel<<<NTOT / 2, 256, 0, stream>>>(qkv, ao);
  // out = ao @ outw^T + outb + bias : M=16000, K=128, N=128
  gemm_kernel<128><<<dim3(125, 2), 256, 0, stream>>>(ao, outw, outb, bias, out, 128);
}

// Round 5
// 171.844 us; speedup vs baseline: 1.0342x; 1.0342x over previous
//
#include <hip/hip_runtime.h>

#define NN 1000
#define HEADS_ 4
#define DM 128
#define EE 64000
#define NTOT 4000
#define ETOT 68000
#define CAP 48   // bucket capacity per dst; active degree ~ Poisson(4)+1

// ---------------------------------------------------------------------------
// Tiled GEMM: C[M][N] = A[M][K] @ Wt[N][K]^T (+ b1[n] + b2[n])
// 128x64 tile, 256 threads, 8x4 micro-tile, K staged in 64-wide chunks.
// LDS m-major with k-group XOR swizzle (staging = direct b128 copies).
// SCORE: fused GAT score epilogue (h-GEMM only; rows<1000 hold the only
//        nonzero h_flat rows; block's 64 cols = heads 2*by, 2*by+1).
// REMAP: epilogue writes row m=node*4+v to final (b*4+v)*1000+n order.
// ---------------------------------------------------------------------------
template <int K, int SCORE, int REMAP>
__global__ __launch_bounds__(256) void gemm_kernel(const float* __restrict__ A,
                                                   const float* __restrict__ Wt,
                                                   const float* __restrict__ b1,
                                                   const float* __restrict__ b2,
                                                   float* __restrict__ C, int N,
                                                   const float* __restrict__ att,
                                                   float* __restrict__ ssrc,
                                                   float* __restrict__ sdst) {
  __shared__ float As[128 * 64];
  __shared__ float Bs[64 * 64];
  int tid = threadIdx.x;
  int m0 = blockIdx.x * 128, n0 = blockIdx.y * 64;
  int tx = tid & 15, ty = tid >> 4;
  const float4* A4 = (const float4*)A;
  const float4* W4 = (const float4*)Wt;
  float acc[8][4] = {};

  for (int c = 0; c < K / 64; ++c) {
    __syncthreads();
    {
      int q = tid & 15;   // k-group slot within chunk
      int r0 = tid >> 4;  // 16 rows per pass
#pragma unroll
      for (int p = 0; p < 8; ++p) {  // A: 128 rows
        int r = r0 + p * 16;
        float4 v = A4[(size_t)(m0 + r) * (K / 4) + c * 16 + q];
        *(float4*)&As[r * 64 + ((q ^ (r & 15)) << 2)] = v;
      }
#pragma unroll
      for (int p = 0; p < 4; ++p) {  // B: 64 rows
        int r = r0 + p * 16;
        float4 v = W4[(size_t)(n0 + r) * (K / 4) + c * 16 + q];
        *(float4*)&Bs[r * 64 + ((q ^ (r & 15)) << 2)] = v;
      }
    }
    __syncthreads();
#pragma unroll 4
    for (int q = 0; q < 16; ++q) {
      float4 a[8], b[4];
#pragma unroll
      for (int i = 0; i < 8; ++i) {
        int r = ty * 8 + i;
        a[i] = *(const float4*)&As[r * 64 + ((q ^ (r & 15)) << 2)];
      }
#pragma unroll
      for (int j = 0; j < 4; ++j) {
        int rn = tx * 4 + j;
        b[j] = *(const float4*)&Bs[rn * 64 + ((q ^ (rn & 15)) << 2)];
      }
#pragma unroll
      for (int i = 0; i < 8; ++i)
#pragma unroll
        for (int j = 0; j < 4; ++j)
          acc[i][j] += a[i].x * b[j].x + a[i].y * b[j].y
                     + a[i].z * b[j].z + a[i].w * b[j].w;
    }
  }

  float bd[4] = {0.f, 0.f, 0.f, 0.f};
  int nc = n0 + tx * 4;
  if (b1) { bd[0] = b1[nc]; bd[1] = b1[nc+1]; bd[2] = b1[nc+2]; bd[3] = b1[nc+3]; }
  if (b2) { bd[0] += b2[nc]; bd[1] += b2[nc+1]; bd[2] += b2[nc+2]; bd[3] += b2[nc+3]; }
#pragma unroll
  for (int i = 0; i < 8; ++i) {
    int m = m0 + ty * 8 + i;
    int om = m;
    if (REMAP) {
      int node = m >> 2, v = m & 3;
      int b = node / NN, n = node - b * NN;
      om = (b * 4 + v) * NN + n;
    }
    float4 o = make_float4(acc[i][0] + bd[0], acc[i][1] + bd[1],
                           acc[i][2] + bd[2], acc[i][3] + bd[3]);
    *(float4*)&C[(size_t)om * N + nc] = o;
  }

  if (SCORE && m0 < NN) {  // uniform branch per block
    int hsel = tx >> 3;                     // which head of this 64-col tile
    int h = (int)blockIdx.y * 2 + hsel;
    int kb = (tx & 7) * 4;                  // k-offset within head
    float a0[4], a1[4];
#pragma unroll
    for (int j = 0; j < 4; ++j) {
      a0[j] = att[h * 64 + kb + j];
      a1[j] = att[h * 64 + 32 + kb + j];
    }
#pragma unroll
    for (int i = 0; i < 8; ++i) {
      int m = m0 + ty * 8 + i;
      float p0 = 0.f, p1 = 0.f;
#pragma unroll
      for (int j = 0; j < 4; ++j) {
        float g = acc[i][j];  // h value (no bias in h-GEMM)
        float lr = g > 0.f ? g : 0.2f * g;
        p0 += a0[j] * lr;
        p1 += a1[j] * lr;
      }
      // reduce across the 8 tx lanes of this head (lanes are consecutive)
      p0 += __shfl_xor(p0, 1, 16); p1 += __shfl_xor(p1, 1, 16);
      p0 += __shfl_xor(p0, 2, 16); p1 += __shfl_xor(p1, 2, 16);
      p0 += __shfl_xor(p0, 4, 16); p1 += __shfl_xor(p1, 4, 16);
      if ((tx & 7) == 0 && m < NN) {
        ssrc[m * HEADS_ + h] = p0;
        sdst[m * HEADS_ + h] = p1;
      }
    }
  }
}

// ---- per-edge exp(score) + denom atomics + direct bucket adjacency build
// denom covers ALL edges (reference softmax); buckets only active edges
// (src,dst in same graph block). Bucket order is irrelevant to the gather.
__global__ void edge_score_kernel(const int* __restrict__ ei,
                                  const float* __restrict__ ssrc,
                                  const float* __restrict__ sdst,
                                  float* __restrict__ exbuf,
                                  float* __restrict__ denom,
                                  int* __restrict__ cnt,
                                  int2* __restrict__ elist) {
  int e = blockIdx.x * blockDim.x + threadIdx.x;
  if (e >= ETOT) return;
  int s, d;
  if (e < EE) { s = ei[e]; d = ei[EE + e]; }
  else { s = d = e - EE; }  // self loops
#pragma unroll
  for (int h = 0; h < HEADS_; ++h) {
    float sc = ssrc[s * HEADS_ + h] + sdst[d * HEADS_ + h];
    float ex = __expf(sc);  // shift-invariant; scores O(1), no max pass needed
    exbuf[e * HEADS_ + h] = ex;
    atomicAdd(&denom[d * HEADS_ + h], ex);
  }
  if (s / NN == d / NN) {
    int pos = atomicAdd(&cnt[d], 1);
    if (pos < CAP) elist[d * CAP + pos] = make_int2(s, e);
  }
}

// ------------------- gather aggregation: 2 dst/block, float4 per thread
// writes hgat NODE-MAJOR: row = d*4 + v  (d = b*NN+n is the node id)
__global__ __launch_bounds__(256) void gather_kernel(const int* __restrict__ cnt,
                                                     const int2* __restrict__ elist,
                                                     const float* __restrict__ exbuf,
                                                     const float* __restrict__ denom,
                                                     const float* __restrict__ hbuf,
                                                     float* __restrict__ hgat) {
  int li = threadIdx.x >> 7;
  int t = threadIdx.x & 127;
  int d = blockIdx.x * 2 + li;  // global dst node id
  int v = t >> 5, q = t & 31;   // view, float4-col
  int h = q >> 3;
  int b = d / NN;
  float rd = 1.f / (denom[d * HEADS_ + h] + 1e-16f);
  float4 acc = make_float4(0.f, 0.f, 0.f, 0.f);
  int m = cnt[d]; if (m > CAP) m = CAP;
  const int2* el = elist + d * CAP;
  const float* hbase = hbuf + ((size_t)(b * 4 + v) * NN) * DM + q * 4;
  for (int i = 0; i < m; ++i) {
    int2 se = el[i];
    float alpha = exbuf[se.y * HEADS_ + h] * rd;
    int sl = se.x - b * NN;
    float4 hv = *(const float4*)(hbase + (size_t)sl * DM);
    acc.x += alpha * hv.x; acc.y += alpha * hv.y;
    acc.z += alpha * hv.z; acc.w += alpha * hv.w;
  }
  *(float4*)&hgat[((size_t)(d * 4 + v)) * DM + q * 4] = acc;
}

// --------------- attention over V, 2 nodes/block, node-major qkv/ao
__global__ __launch_bounds__(256) void attn_kernel(const float* __restrict__ qkv,
                                                   float* __restrict__ ao) {
  int li = threadIdx.x >> 7;
  int t = threadIdx.x & 127;
  int node = blockIdx.x * 2 + li;  // 0..3999
  __shared__ float qs[2][4][DM], ks[2][4][DM], vs[2][4][DM];
  __shared__ float aw[2][4][HEADS_][4];
#pragma unroll
  for (int v = 0; v < 4; ++v) {
    size_t base = (size_t)(node * 4 + v) * 384;  // contiguous rows now
    qs[li][v][t] = qkv[base + t];
    ks[li][v][t] = qkv[base + 128 + t];
    vs[li][v][t] = qkv[base + 256 + t];
  }
  __syncthreads();
  if (t < 64) {  // (vq, vk, h) dot products, length 32
    int vq = t >> 4, vk = (t >> 2) & 3, h = t & 3;
    float acc = 0.f;
#pragma unroll
    for (int kd = 0; kd < 32; ++kd)
      acc += qs[li][vq][h * 32 + kd] * ks[li][vk][h * 32 + kd];
    aw[li][vq][h][vk] = acc * 0.17677669529663687f;  // 1/sqrt(32)
  }
  __syncthreads();
  if (t < 16) {  // softmax over vk per (vq, h)
    int vq = t >> 2, h = t & 3;
    float m = aw[li][vq][h][0];
    for (int i = 1; i < 4; ++i) m = fmaxf(m, aw[li][vq][h][i]);
    float e[4], s = 0.f;
    for (int i = 0; i < 4; ++i) { e[i] = __expf(aw[li][vq][h][i] - m); s += e[i]; }
    for (int i = 0; i < 4; ++i) aw[li][vq][h][i] = e[i] / s;
  }
  __syncthreads();
  int h = t >> 5;
#pragma unroll
  for (int vq = 0; vq < 4; ++vq) {
    float acc = 0.f;
#pragma unroll
    for (int vk = 0; vk < 4; ++vk) acc += aw[li][vq][h][vk] * vs[li][vk][t];
    ao[(size_t)(node * 4 + vq) * DM + t] = acc;
  }
}

extern "C" void kernel_launch(void* const* d_in, const int* in_sizes, int n_in,
                              void* d_out, int out_size, void* d_ws, size_t ws_size,
                              hipStream_t stream) {
  const float* x    = (const float*)d_in[0];
  const float* W    = (const float*)d_in[1];
  const float* att  = (const float*)d_in[2];
  const float* inw  = (const float*)d_in[3];
  const float* inb  = (const float*)d_in[4];
  const float* outw = (const float*)d_in[5];
  const float* outb = (const float*)d_in[6];
  const float* bias = (const float*)d_in[7];
  const int*   ei   = (const int*)d_in[8];
  float* out = (float*)d_out;

  float* ws = (float*)d_ws;
  // no aliasing — ws is large (268 MB); we use ~53 MB
  float* hbuf  = ws;                        // (b,v,n)-major h      2,048,000
  float* hgat  = ws + 2100000;              // node-major hgat      2,048,000
  float* qkv   = ws + 4200000;              // node-major qkv       6,144,000
  float* ao    = ws + 10400000;             // node-major ao        2,048,000
  float* ssrc  = ws + 12500000;             // 16,000  } one
  float* sdst  = ssrc + 16000;              // 16,000  } contiguous
  float* denom = sdst + 16000;              // 16,000  } memset
  int*   cnt   = (int*)(denom + 16000);     //  4,000  }
  float* exbuf = (float*)(cnt + 4000);      // 272,000
  int2*  elist = (int2*)(exbuf + 272000);   // 192,000 int2

  // zero ssrc/sdst (rows >=1000 stay zero), denom, cnt in one memset
  hipMemsetAsync(ssrc, 0, 52000 * sizeof(float), stream);

  // h = x @ W^T (M=16000,K=64,N=128) + fused GAT score epilogue
  gemm_kernel<64, 1, 0><<<dim3(125, 2), 256, 0, stream>>>(
      x, W, nullptr, nullptr, hbuf, 128, att, ssrc, sdst);
  edge_score_kernel<<<(ETOT + 255) / 256, 256, 0, stream>>>(
      ei, ssrc, sdst, exbuf, denom, cnt, elist);
  gather_kernel<<<NTOT / 2, 256, 0, stream>>>(cnt, elist, exbuf, denom, hbuf, hgat);
  // qkv = hgat @ inw^T + inb (M=16000,K=128,N=384), node-major in/out
  gemm_kernel<128, 0, 0><<<dim3(125, 6), 256, 0, stream>>>(
      hgat, inw, inb, nullptr, qkv, 384, nullptr, nullptr, nullptr);
  attn_kernel<<<NTOT / 2, 256, 0, stream>>>(qkv, ao);
  // out = ao @ outw^T + outb + bias (M=16000,K=128,N=128), remap to (b,v,n)
  gemm_kernel<128, 0, 1><<<dim3(125, 2), 256, 0, stream>>>(
      ao, outw, outb, bias, out, 128, nullptr, nullptr, nullptr);
}